// Round 10
// baseline (291.402 us; speedup 1.0000x reference)
//
#include <hip/hip_runtime.h>

typedef __attribute__((ext_vector_type(8))) short s8v;   // 8 bf16
typedef __attribute__((ext_vector_type(4))) short s4v;   // 4 bf16
typedef __attribute__((ext_vector_type(4))) float f4v;   // MFMA C/D

#define S_ 4096
#define E_ 1024
#define D_ 128

__device__ __forceinline__ unsigned short f2bf(float f) {
  unsigned int u = __float_as_uint(f);
  return (unsigned short)((u + 0x7FFFu + ((u >> 16) & 1u)) >> 16);
}

// async global->LDS, 16B per lane; LDS dest = wave-uniform base + lane*16
__device__ __forceinline__ void gload16(const void* g, void* l) {
  __builtin_amdgcn_global_load_lds(
      (const __attribute__((address_space(1))) unsigned int*)g,
      (__attribute__((address_space(3))) unsigned int*)l, 16, 0, 0);
}

// packed partial-slot row offset: slot s covers q-rows [512s, 4096)
__device__ __forceinline__ int slot_off(int s) { return s * (3840 - 256 * s); }

// ---- prep: xcvt (blocks 0..8191) + wcvt (blocks 8192..8287) ---------------
__global__ __launch_bounds__(256) void prep_kernel(
    const float* __restrict__ x, const float* __restrict__ Wq,
    const float* __restrict__ Wk, const float* __restrict__ Wv,
    unsigned short* __restrict__ Xb, unsigned short* __restrict__ Wt) {
  __shared__ unsigned short T[64][72];
  const int bid = blockIdx.x;
  if (bid < 8192) {  // x f32 -> bf16
    const size_t i = ((size_t)bid * 256 + threadIdx.x) * 8;
    float4 a = *reinterpret_cast<const float4*>(x + i);
    float4 c = *reinterpret_cast<const float4*>(x + i + 4);
    s8v v;
    v[0] = (short)f2bf(a.x); v[1] = (short)f2bf(a.y);
    v[2] = (short)f2bf(a.z); v[3] = (short)f2bf(a.w);
    v[4] = (short)f2bf(c.x); v[5] = (short)f2bf(c.y);
    v[6] = (short)f2bf(c.z); v[7] = (short)f2bf(c.w);
    *reinterpret_cast<s8v*>(Xb + i) = v;
  } else {  // W cvt+transpose: W[p][k][n] f32 -> Wt[p*128+n][k] bf16
    const int w = bid - 8192;
    const int p = w >> 5, bx = w & 31;
    const float* W = (p == 0) ? Wq : (p == 1) ? Wk : Wv;
    const int k0 = (bx >> 1) * 64;
    const int n0 = (bx & 1) * 64;
    const int t = threadIdx.x, rr = t >> 4, c4 = (t & 15) * 4;
#pragma unroll
    for (int i = 0; i < 4; ++i) {
      int kr = i * 16 + rr;
      float4 ww = *reinterpret_cast<const float4*>(W + (size_t)(k0 + kr) * D_ + n0 + c4);
      T[c4 + 0][kr] = f2bf(ww.x); T[c4 + 1][kr] = f2bf(ww.y);
      T[c4 + 2][kr] = f2bf(ww.z); T[c4 + 3][kr] = f2bf(ww.w);
    }
    __syncthreads();
#pragma unroll
    for (int i = 0; i < 4; ++i) {
      int n = i * 16 + rr;
      s4v v;
      v[0] = (short)T[n][c4]; v[1] = (short)T[n][c4 + 1];
      v[2] = (short)T[n][c4 + 2]; v[3] = (short)T[n][c4 + 3];
      *reinterpret_cast<s4v*>(Wt + (size_t)(p * D_ + n0 + n) * E_ + k0 + c4) = v;
    }
  }
}

// ---- fused QKV projection v3 (R3-proven): BM=128, BN=64, BK=64, grid 768 ---
__global__ __launch_bounds__(256, 3) void proj_kernel(
    const unsigned short* __restrict__ Xb, const unsigned short* __restrict__ Wt,
    unsigned short* __restrict__ Qb, unsigned short* __restrict__ Kb,
    unsigned short* __restrict__ VT) {
  __shared__ __align__(16) unsigned short As[128 * 64];
  __shared__ __align__(16) unsigned short Bs[64 * 64];
  const int bid = blockIdx.x;
  const int cls = bid & 7, j = bid >> 3;            // j 0..95
  const int m0 = (cls * 16 + j / 6) * 128, ng = j % 6;
  const int t = threadIdx.x;
  const int wv = t >> 6, lane = t & 63, quad = lane >> 4, l16 = lane & 15;
  const int wr = wv >> 1, wc = wv & 1;  // wave-tile 64x32

  f4v acc[4][2];
  const f4v fz = {0.f, 0.f, 0.f, 0.f};
#pragma unroll
  for (int i = 0; i < 4; ++i)
#pragma unroll
    for (int k = 0; k < 2; ++k) acc[i][k] = fz;

  const int lrow = lane >> 3;
  const int scb = ((lane & 7) ^ lrow) * 16;  // pre-swizzled byte col
  const char* aSrc = (const char*)(Xb + (size_t)(m0 + wv * 32 + lrow) * E_) + scb;
  const char* bSrc = (const char*)(Wt + (size_t)(ng * 64 + wv * 16 + lrow) * E_) + scb;
  char* aDst = (char*)As + wv * 4096;
  char* bDst = (char*)Bs + wv * 2048;

  const int xm = (l16 & 7) * 16;  // read-side swizzle mask
  const char* Ab = (const char*)As + (wr * 64 + l16) * 128;
  const char* Bb = (const char*)Bs + (wc * 32 + l16) * 128;

  for (int kk = 0; kk < E_; kk += 64) {
#pragma unroll
    for (int i = 0; i < 4; ++i)
      gload16(aSrc + (size_t)(i * 8 * E_ + kk) * 2, aDst + i * 1024);
#pragma unroll
    for (int i = 0; i < 2; ++i)
      gload16(bSrc + (size_t)(i * 8 * E_ + kk) * 2, bDst + i * 1024);
    __syncthreads();  // drains vmcnt then barrier: LDS tile complete
#pragma unroll
    for (int ks = 0; ks < 2; ++ks) {
      const int co = (ks * 64 + quad * 16) ^ xm;
      s8v af[4], bf[2];
#pragma unroll
      for (int rt = 0; rt < 4; ++rt)
        af[rt] = *reinterpret_cast<const s8v*>(Ab + rt * 2048 + co);
#pragma unroll
      for (int ct = 0; ct < 2; ++ct)
        bf[ct] = *reinterpret_cast<const s8v*>(Bb + ct * 2048 + co);
#pragma unroll
      for (int rt = 0; rt < 4; ++rt)
#pragma unroll
        for (int ct = 0; ct < 2; ++ct)
          acc[rt][ct] = __builtin_amdgcn_mfma_f32_16x16x32_bf16(
              af[rt], bf[ct], acc[rt][ct], 0, 0, 0);
    }
    __syncthreads();  // before overwriting LDS next iter
  }

  const int p = ng >> 1, n0 = (ng & 1) * 64;
  if (p < 2) {
    unsigned short* dst = p ? Kb : Qb;
#pragma unroll
    for (int rt = 0; rt < 4; ++rt)
#pragma unroll
      for (int ct = 0; ct < 2; ++ct)
#pragma unroll
        for (int r = 0; r < 4; ++r)
          dst[(size_t)(m0 + wr * 64 + rt * 16 + quad * 4 + r) * D_ +
              n0 + wc * 32 + ct * 16 + l16] = f2bf(acc[rt][ct][r]);
  } else {
    const int b = m0 >> 12;
    const int s0 = (m0 & (S_ - 1)) + wr * 64;
#pragma unroll
    for (int rt = 0; rt < 4; ++rt)
#pragma unroll
      for (int ct = 0; ct < 2; ++ct) {
        s4v v;
        v[0] = (short)f2bf(acc[rt][ct][0]); v[1] = (short)f2bf(acc[rt][ct][1]);
        v[2] = (short)f2bf(acc[rt][ct][2]); v[3] = (short)f2bf(acc[rt][ct][3]);
        *reinterpret_cast<s4v*>(
            VT + ((size_t)b * D_ + n0 + wc * 32 + ct * 16 + l16) * S_ + s0 +
            rt * 16 + quad * 4) = v;
      }
  }
}

// ---- flash v10: NO LDS, NO BARRIERS — direct-global MFMA fragments ---------
// The QK fragment rows satisfy sig(row)=l16, so the staged-LDS read was
// byte-identical to a per-lane global load: kf = Kbb[(k0+row)*D + g*8],
// vf = Vbb[(d)*S + k0 + g*8] (like Qf already does). K/V tiles (16KB each,
// 2MB/batch) are L1/L2-resident; 4 waves/block share via L1. No staging, no
// __syncthreads, per-wave causal loop bound, compiler hoists next-iter loads
// under PV (no fence). LDS=0: occupancy VGPR-bound only.
__global__ __launch_bounds__(256, 4) void flash_kernel(
    const unsigned short* __restrict__ Qb, const unsigned short* __restrict__ Kb,
    const unsigned short* __restrict__ VT, float* __restrict__ Op,
    float* __restrict__ Lp) {
  const int id = blockIdx.x;
  const int xcd = id & 7;
  const int b = xcd >> 1;
  const int sub = 287 - ((id >> 3) * 2 + (xcd & 1));  // heavy-first
  int g = 0;
#pragma unroll
  for (int gg = 0; gg < 7; ++gg)
    if (sub >= 4 * (gg + 1) * (gg + 2)) g = gg + 1;
  const int off = sub - 4 * g * (g + 1);
  const int qt = 8 * g + off / (g + 1);
  const int s = off % (g + 1);
  const int q0 = qt * 64;
  const int klo = s * 512;
  const int khi = min((s + 1) * 512, (qt + 1) * 64);

  const int t = threadIdx.x;
  const int wv = t >> 6, lane = t & 63, quad = lane >> 4, l16 = lane & 15;
  const int qrow0 = q0 + wv * 16;
  const float SCL2 = 0.03125f * 1.44269504088896340736f;  // (1/32)*log2(e)

  const unsigned short* Kbb = Kb + (size_t)b * S_ * D_;
  const unsigned short* Vbb = VT + (size_t)b * D_ * S_;

  s8v Qf[4];
#pragma unroll
  for (int ks = 0; ks < 4; ++ks)
    Qf[ks] = *reinterpret_cast<const s8v*>(
        Qb + ((size_t)b * S_ + qrow0 + l16) * D_ + ks * 32 + quad * 8);

  f4v O[8];
  const f4v fz = {0.f, 0.f, 0.f, 0.f};
#pragma unroll
  for (int nt = 0; nt < 8; ++nt) O[nt] = fz;
  float lt = 0.f;

  // QK fragment row base (sig(row) == l16 identity)
  const int rbase = ((l16 >> 2) << 3) + (l16 & 3);
  // per-wave causal bound: iters need k0 <= qrow0+15; klo <= q0 always
  const int khiw = min(khi, qrow0 + 16);

  for (int k0 = klo; k0 < khiw; k0 += 64) {
    f4v St[2][2];  // [chunk c][s2]
#pragma unroll
    for (int c = 0; c < 2; ++c)
#pragma unroll
      for (int s2 = 0; s2 < 2; ++s2) St[c][s2] = fz;
    __builtin_amdgcn_s_setprio(1);
#pragma unroll
    for (int ks = 0; ks < 4; ++ks) {
      s8v kf[2][2];
#pragma unroll
      for (int c = 0; c < 2; ++c)
#pragma unroll
        for (int s2 = 0; s2 < 2; ++s2)
          kf[c][s2] = *reinterpret_cast<const s8v*>(
              Kbb + (size_t)(k0 + c * 32 + s2 * 4 + rbase) * D_ +
              (ks * 4 + quad) * 8);
#pragma unroll
      for (int c = 0; c < 2; ++c)
#pragma unroll
        for (int s2 = 0; s2 < 2; ++s2)
          St[c][s2] = __builtin_amdgcn_mfma_f32_16x16x32_bf16(
              kf[c][s2], Qf[ks], St[c][s2], 0, 0, 0);
    }
    __builtin_amdgcn_s_setprio(0);
    const bool full = (k0 + 63 <= qrow0);
    s8v pf[2];  // [c]
#pragma unroll
    for (int c = 0; c < 2; ++c) {
      float ladd = 0.f;
#pragma unroll
      for (int s2 = 0; s2 < 2; ++s2)
#pragma unroll
        for (int r = 0; r < 4; ++r) {
          float e = exp2f(St[c][s2][r] * SCL2);
          if (!full) {
            int key = k0 + c * 32 + quad * 8 + s2 * 4 + r;
            if (key > qrow0 + l16) e = 0.f;
          }
          ladd += e;
          pf[c][s2 * 4 + r] = (short)f2bf(e);
        }
      lt += ladd;
    }
    __builtin_amdgcn_s_setprio(1);
#pragma unroll
    for (int c = 0; c < 2; ++c)
#pragma unroll
      for (int nt = 0; nt < 8; ++nt) {
        s8v vf = *reinterpret_cast<const s8v*>(
            Vbb + (size_t)(nt * 16 + l16) * S_ + k0 + (c * 4 + quad) * 8);
        O[nt] = __builtin_amdgcn_mfma_f32_16x16x32_bf16(
            pf[c], vf, O[nt], 0, 0, 0);
      }
    __builtin_amdgcn_s_setprio(0);
  }

  // epilogue: plain stores to this (qt,s)-chunk's private packed slot
  lt += __shfl_xor(lt, 16);
  lt += __shfl_xor(lt, 32);
  const int soff = slot_off(s);
#pragma unroll
  for (int nt = 0; nt < 8; ++nt)
#pragma unroll
    for (int r = 0; r < 4; ++r)
      Op[((size_t)(qrow0 + quad * 4 + r + soff) * 4 + b) * D_ + nt * 16 + l16] =
          O[nt][r];
  if (lane < 16) Lp[(size_t)(qrow0 + l16 + soff) * 4 + b] = lt;
}

// ---- normalize: out[b][row][:] = sum_s Op_s / sum_s Lp_s -------------------
__global__ __launch_bounds__(256) void norm_kernel(
    const float* __restrict__ Op, const float* __restrict__ Lp,
    float* __restrict__ out) {
  const int idx = blockIdx.x * 256 + threadIdx.x;  // float4 index
  const int rowg = idx >> 5, d4 = idx & 31;        // 32 float4 per row
  const int b = rowg >> 12, row = rowg & 4095;
  const int g = row >> 9;  // chunks-1 for this row
  float ax = 0.f, ay = 0.f, az = 0.f, aw = 0.f, L = 0.f;
  for (int s = 0; s <= g; ++s) {
    const size_t pr = (size_t)(row + slot_off(s)) * 4 + b;
    float4 o = reinterpret_cast<const float4*>(Op + pr * D_)[d4];
    ax += o.x; ay += o.y; az += o.z; aw += o.w;
    L += Lp[pr];
  }
  float4 r;
  const float inv = 1.f / L;
  r.x = ax * inv; r.y = ay * inv; r.z = az * inv; r.w = aw * inv;
  reinterpret_cast<float4*>(out)[idx] = r;
}

extern "C" void kernel_launch(void* const* d_in, const int* in_sizes, int n_in,
                              void* d_out, int out_size, void* d_ws, size_t ws_size,
                              hipStream_t stream) {
  const float* x = (const float*)d_in[0];
  const float* Wq = (const float*)d_in[1];
  const float* Wk = (const float*)d_in[2];
  const float* Wv = (const float*)d_in[3];
  float* out = (float*)d_out;

  char* ws = (char*)d_ws;
  unsigned short* Qb = (unsigned short*)ws;                           // 4 MB
  unsigned short* Kb = (unsigned short*)(ws + (((size_t)4) << 20));   // 4 MB
  unsigned short* VT = (unsigned short*)(ws + (((size_t)8) << 20));   // 4 MB
  unsigned short* Wt = (unsigned short*)(ws + (((size_t)12) << 20));  // 0.75 MB
  // Xb (32 MB) aliases Op (36 MB): Xb is consumed by proj BEFORE flash
  // writes Op (stream-ordered). Total workspace: ~50.5 MB.
  unsigned short* Xb = (unsigned short*)(ws + (((size_t)13) << 20));  // 32 MB
  float* Op = (float*)(ws + (((size_t)13) << 20));                    // 36 MB
  float* Lp = (float*)(ws + (((size_t)50) << 20));                    // 0.3 MB

  prep_kernel<<<8288, 256, 0, stream>>>(x, Wq, Wk, Wv, Xb, Wt);
  proj_kernel<<<768, 256, 0, stream>>>(Xb, Wt, Qb, Kb, VT);
  flash_kernel<<<1152, 256, 0, stream>>>(Qb, Kb, VT, Op, Lp);
  norm_kernel<<<2048, 256, 0, stream>>>(Op, Lp, out);
}

// Round 11
// 173.272 us; speedup vs baseline: 1.6818x; 1.6818x over previous
//
#include <hip/hip_runtime.h>

typedef __attribute__((ext_vector_type(8))) short s8v;   // 8 bf16
typedef __attribute__((ext_vector_type(4))) short s4v;   // 4 bf16
typedef __attribute__((ext_vector_type(4))) float f4v;   // MFMA C/D

#define S_ 4096
#define E_ 1024
#define D_ 128

__device__ __forceinline__ unsigned short f2bf(float f) {
  unsigned int u = __float_as_uint(f);
  return (unsigned short)((u + 0x7FFFu + ((u >> 16) & 1u)) >> 16);
}

// async global->LDS, 16B per lane; LDS dest = wave-uniform base + lane*16
__device__ __forceinline__ void gload16(const void* g, void* l) {
  __builtin_amdgcn_global_load_lds(
      (const __attribute__((address_space(1))) unsigned int*)g,
      (__attribute__((address_space(3))) unsigned int*)l, 16, 0, 0);
}

// packed partial-slot row offset, 1024-key chunks: slot s serves rows
// [1024s, 4096); position = row + slot_off(s). off(1)=3072 off(2)=5120
// off(3)=6144; max pos 10239 -> Op = 10240*4*128 f32 = 21 MB.
__device__ __forceinline__ int slot_off(int s) { return s * (3584 - 512 * s); }

// ---- prep: xcvt (blocks 0..8191) + wcvt (blocks 8192..8287) ---------------
__global__ __launch_bounds__(256) void prep_kernel(
    const float* __restrict__ x, const float* __restrict__ Wq,
    const float* __restrict__ Wk, const float* __restrict__ Wv,
    unsigned short* __restrict__ Xb, unsigned short* __restrict__ Wt) {
  __shared__ unsigned short T[64][72];
  const int bid = blockIdx.x;
  if (bid < 8192) {  // x f32 -> bf16
    const size_t i = ((size_t)bid * 256 + threadIdx.x) * 8;
    float4 a = *reinterpret_cast<const float4*>(x + i);
    float4 c = *reinterpret_cast<const float4*>(x + i + 4);
    s8v v;
    v[0] = (short)f2bf(a.x); v[1] = (short)f2bf(a.y);
    v[2] = (short)f2bf(a.z); v[3] = (short)f2bf(a.w);
    v[4] = (short)f2bf(c.x); v[5] = (short)f2bf(c.y);
    v[6] = (short)f2bf(c.z); v[7] = (short)f2bf(c.w);
    *reinterpret_cast<s8v*>(Xb + i) = v;
  } else {  // W cvt+transpose: W[p][k][n] f32 -> Wt[p*128+n][k] bf16
    const int w = bid - 8192;
    const int p = w >> 5, bx = w & 31;
    const float* W = (p == 0) ? Wq : (p == 1) ? Wk : Wv;
    const int k0 = (bx >> 1) * 64;
    const int n0 = (bx & 1) * 64;
    const int t = threadIdx.x, rr = t >> 4, c4 = (t & 15) * 4;
#pragma unroll
    for (int i = 0; i < 4; ++i) {
      int kr = i * 16 + rr;
      float4 ww = *reinterpret_cast<const float4*>(W + (size_t)(k0 + kr) * D_ + n0 + c4);
      T[c4 + 0][kr] = f2bf(ww.x); T[c4 + 1][kr] = f2bf(ww.y);
      T[c4 + 2][kr] = f2bf(ww.z); T[c4 + 3][kr] = f2bf(ww.w);
    }
    __syncthreads();
#pragma unroll
    for (int i = 0; i < 4; ++i) {
      int n = i * 16 + rr;
      s4v v;
      v[0] = (short)T[n][c4]; v[1] = (short)T[n][c4 + 1];
      v[2] = (short)T[n][c4 + 2]; v[3] = (short)T[n][c4 + 3];
      *reinterpret_cast<s4v*>(Wt + (size_t)(p * D_ + n0 + n) * E_ + k0 + c4) = v;
    }
  }
}

// ---- fused QKV projection v3 (R3-proven): BM=128, BN=64, BK=64, grid 768 ---
__global__ __launch_bounds__(256, 3) void proj_kernel(
    const unsigned short* __restrict__ Xb, const unsigned short* __restrict__ Wt,
    unsigned short* __restrict__ Qb, unsigned short* __restrict__ Kb,
    unsigned short* __restrict__ VT) {
  __shared__ __align__(16) unsigned short As[128 * 64];
  __shared__ __align__(16) unsigned short Bs[64 * 64];
  const int bid = blockIdx.x;
  const int cls = bid & 7, j = bid >> 3;            // j 0..95
  const int m0 = (cls * 16 + j / 6) * 128, ng = j % 6;
  const int t = threadIdx.x;
  const int wv = t >> 6, lane = t & 63, quad = lane >> 4, l16 = lane & 15;
  const int wr = wv >> 1, wc = wv & 1;  // wave-tile 64x32

  f4v acc[4][2];
  const f4v fz = {0.f, 0.f, 0.f, 0.f};
#pragma unroll
  for (int i = 0; i < 4; ++i)
#pragma unroll
    for (int k = 0; k < 2; ++k) acc[i][k] = fz;

  const int lrow = lane >> 3;
  const int scb = ((lane & 7) ^ lrow) * 16;  // pre-swizzled byte col
  const char* aSrc = (const char*)(Xb + (size_t)(m0 + wv * 32 + lrow) * E_) + scb;
  const char* bSrc = (const char*)(Wt + (size_t)(ng * 64 + wv * 16 + lrow) * E_) + scb;
  char* aDst = (char*)As + wv * 4096;
  char* bDst = (char*)Bs + wv * 2048;

  const int xm = (l16 & 7) * 16;  // read-side swizzle mask
  const char* Ab = (const char*)As + (wr * 64 + l16) * 128;
  const char* Bb = (const char*)Bs + (wc * 32 + l16) * 128;

  for (int kk = 0; kk < E_; kk += 64) {
#pragma unroll
    for (int i = 0; i < 4; ++i)
      gload16(aSrc + (size_t)(i * 8 * E_ + kk) * 2, aDst + i * 1024);
#pragma unroll
    for (int i = 0; i < 2; ++i)
      gload16(bSrc + (size_t)(i * 8 * E_ + kk) * 2, bDst + i * 1024);
    __syncthreads();  // drains vmcnt then barrier: LDS tile complete
#pragma unroll
    for (int ks = 0; ks < 2; ++ks) {
      const int co = (ks * 64 + quad * 16) ^ xm;
      s8v af[4], bf[2];
#pragma unroll
      for (int rt = 0; rt < 4; ++rt)
        af[rt] = *reinterpret_cast<const s8v*>(Ab + rt * 2048 + co);
#pragma unroll
      for (int ct = 0; ct < 2; ++ct)
        bf[ct] = *reinterpret_cast<const s8v*>(Bb + ct * 2048 + co);
#pragma unroll
      for (int rt = 0; rt < 4; ++rt)
#pragma unroll
        for (int ct = 0; ct < 2; ++ct)
          acc[rt][ct] = __builtin_amdgcn_mfma_f32_16x16x32_bf16(
              af[rt], bf[ct], acc[rt][ct], 0, 0, 0);
    }
    __syncthreads();  // before overwriting LDS next iter
  }

  const int p = ng >> 1, n0 = (ng & 1) * 64;
  if (p < 2) {
    unsigned short* dst = p ? Kb : Qb;
#pragma unroll
    for (int rt = 0; rt < 4; ++rt)
#pragma unroll
      for (int ct = 0; ct < 2; ++ct)
#pragma unroll
        for (int r = 0; r < 4; ++r)
          dst[(size_t)(m0 + wr * 64 + rt * 16 + quad * 4 + r) * D_ +
              n0 + wc * 32 + ct * 16 + l16] = f2bf(acc[rt][ct][r]);
  } else {
    const int b = m0 >> 12;
    const int s0 = (m0 & (S_ - 1)) + wr * 64;
#pragma unroll
    for (int rt = 0; rt < 4; ++rt)
#pragma unroll
      for (int ct = 0; ct < 2; ++ct) {
        s4v v;
        v[0] = (short)f2bf(acc[rt][ct][0]); v[1] = (short)f2bf(acc[rt][ct][1]);
        v[2] = (short)f2bf(acc[rt][ct][2]); v[3] = (short)f2bf(acc[rt][ct][3]);
        *reinterpret_cast<s4v*>(
            VT + ((size_t)b * D_ + n0 + wc * 32 + ct * 16 + l16) * S_ + s0 +
            rt * 16 + quad * 4) = v;
      }
  }
}

// ---- flash v11: R3-proven core, 1024-key chunks, direct-write g==0 ---------
// grid 640 (all blocks co-resident at 4/CU): xcd = id&7 -> (batch, half);
// sub = heavy-first over 160 (qt,s) pairs/batch. Tile group g (16 tiles,
// qt in [16g,16g+15]) has g+1 chunks; cumulative before group g = 8g(g+1).
// Single-chunk tiles (g==0, rows 0..1023) normalize in-register and write
// out directly (no Op/Lp, no fence — own data). Others write packed slots.
__global__ __launch_bounds__(256, 4) void flash_kernel(
    const unsigned short* __restrict__ Qb, const unsigned short* __restrict__ Kb,
    const unsigned short* __restrict__ VT, float* __restrict__ Op,
    float* __restrict__ Lp, float* __restrict__ out) {
  __shared__ __align__(16) unsigned short KS[64 * 128];
  __shared__ __align__(16) unsigned short VS[128 * 72];
  const int id = blockIdx.x;
  const int xcd = id & 7;
  const int b = xcd >> 1;
  const int sub = 159 - ((id >> 3) * 2 + (xcd & 1));  // heavy-first
  int g = 0;
#pragma unroll
  for (int gg = 0; gg < 3; ++gg)
    if (sub >= 8 * (gg + 1) * (gg + 2)) g = gg + 1;
  const int off = sub - 8 * g * (g + 1);
  const int qt = 16 * g + off / (g + 1);
  const int s = off % (g + 1);
  const int q0 = qt * 64;
  const int klo = s * 1024;
  const int khi = min((s + 1) * 1024, (qt + 1) * 64);

  const int t = threadIdx.x;
  const int wv = t >> 6, lane = t & 63, quad = lane >> 4, l16 = lane & 15;
  const int qrow0 = q0 + wv * 16;
  const float SCL2 = 0.03125f * 1.44269504088896340736f;  // (1/32)*log2(e)

  const unsigned short* Kbb = Kb + (size_t)b * S_ * D_;
  const unsigned short* Vbb = VT + (size_t)b * D_ * S_;

  s8v Qf[4];
#pragma unroll
  for (int ks = 0; ks < 4; ++ks)
    Qf[ks] = *reinterpret_cast<const s8v*>(
        Qb + ((size_t)b * S_ + qrow0 + l16) * D_ + ks * 32 + quad * 8);

  f4v O[8];
  const f4v fz = {0.f, 0.f, 0.f, 0.f};
#pragma unroll
  for (int nt = 0; nt < 8; ++nt) O[nt] = fz;
  float lt = 0.f;

  // staging: K rows krow+16i (granule kgb); V d-rows vrow (granules vgb+i)
  const int krow = t >> 4, kgb = t & 15;
  const int vrow = t >> 1, vgb = (t & 1) * 4;

  s8v kr[4], vr[4];
#pragma unroll
  for (int i = 0; i < 4; ++i) {
    kr[i] = *reinterpret_cast<const s8v*>(
        Kbb + (size_t)(klo + krow + 16 * i) * D_ + kgb * 8);
    vr[i] = *reinterpret_cast<const s8v*>(
        Vbb + (size_t)vrow * S_ + klo + (vgb + i) * 8);
  }

  for (int k0 = klo; k0 < khi; k0 += 64) {
    __syncthreads();
#pragma unroll
    for (int i = 0; i < 4; ++i) {
      const int r = krow + 16 * i;
      const int sig = (krow & 3) | ((((krow >> 3) + 2 * i) & 3) << 2);
      *reinterpret_cast<s8v*>(KS + r * 128 + ((kgb ^ sig) * 8)) = kr[i];
      *reinterpret_cast<s8v*>(VS + vrow * 72 + (vgb + i) * 8) = vr[i];
    }
    __syncthreads();
    if (k0 + 64 < khi) {  // issue next-tile loads; in flight during compute
#pragma unroll
      for (int i = 0; i < 4; ++i) {
        kr[i] = *reinterpret_cast<const s8v*>(
            Kbb + (size_t)(k0 + 64 + krow + 16 * i) * D_ + kgb * 8);
        vr[i] = *reinterpret_cast<const s8v*>(
            Vbb + (size_t)vrow * S_ + k0 + 64 + (vgb + i) * 8);
      }
    }

    if (k0 <= qrow0 + 15) {  // wave-uniform causal skip
      f4v St[2][2];  // [chunk c][s2]
#pragma unroll
      for (int c = 0; c < 2; ++c)
#pragma unroll
        for (int s2 = 0; s2 < 2; ++s2) St[c][s2] = fz;
      __builtin_amdgcn_s_setprio(1);
#pragma unroll
      for (int ks = 0; ks < 4; ++ks)
#pragma unroll
        for (int c = 0; c < 2; ++c)
#pragma unroll
          for (int s2 = 0; s2 < 2; ++s2) {
            const int row = c * 32 + ((l16 >> 2) << 3) + s2 * 4 + (l16 & 3);
            s8v kf = *reinterpret_cast<const s8v*>(
                KS + row * 128 + (((ks * 4 + quad) ^ l16) * 8));
            St[c][s2] = __builtin_amdgcn_mfma_f32_16x16x32_bf16(
                kf, Qf[ks], St[c][s2], 0, 0, 0);
          }
      __builtin_amdgcn_s_setprio(0);
      const bool full = (k0 + 63 <= qrow0);
      s8v pf[2];  // [c]
#pragma unroll
      for (int c = 0; c < 2; ++c) {
        float ladd = 0.f;
#pragma unroll
        for (int s2 = 0; s2 < 2; ++s2)
#pragma unroll
          for (int r = 0; r < 4; ++r) {
            float e = exp2f(St[c][s2][r] * SCL2);
            if (!full) {
              int key = k0 + c * 32 + quad * 8 + s2 * 4 + r;
              if (key > qrow0 + l16) e = 0.f;
            }
            ladd += e;
            pf[c][s2 * 4 + r] = (short)f2bf(e);
          }
        lt += ladd;
      }
      __builtin_amdgcn_s_setprio(1);
#pragma unroll
      for (int c = 0; c < 2; ++c)
#pragma unroll
        for (int nt = 0; nt < 8; ++nt) {
          s8v vf = *reinterpret_cast<const s8v*>(
              VS + (nt * 16 + l16) * 72 + (c * 4 + quad) * 8);
          O[nt] = __builtin_amdgcn_mfma_f32_16x16x32_bf16(
              pf[c], vf, O[nt], 0, 0, 0);
        }
      __builtin_amdgcn_s_setprio(0);
    }
  }

  // row-sum: lanes with same l16 hold the same q-row set; after this each
  // lane's lt = full denominator of row qrow0 + l16.
  lt += __shfl_xor(lt, 16);
  lt += __shfl_xor(lt, 32);

  if (g == 0) {
    // single-chunk tile: normalize in-register, write out directly.
    // O[nt][r] is row qrow0+quad*4+r -> fetch its denominator via shuffle.
    float Lr[4];
#pragma unroll
    for (int r = 0; r < 4; ++r) Lr[r] = 1.f / __shfl(lt, quad * 4 + r);
    float* ob = out + ((size_t)b * S_ + qrow0 + quad * 4) * D_;
#pragma unroll
    for (int nt = 0; nt < 8; ++nt)
#pragma unroll
      for (int r = 0; r < 4; ++r)
        ob[(size_t)r * D_ + nt * 16 + l16] = O[nt][r] * Lr[r];
  } else {
    // partial: plain stores to this (qt,s)-chunk's private packed slot
    const int soff = slot_off(s);
#pragma unroll
    for (int nt = 0; nt < 8; ++nt)
#pragma unroll
      for (int r = 0; r < 4; ++r)
        Op[((size_t)(qrow0 + quad * 4 + r + soff) * 4 + b) * D_ + nt * 16 + l16] =
            O[nt][r];
    if (lane < 16) Lp[(size_t)(qrow0 + l16 + soff) * 4 + b] = lt;
  }
}

// ---- normalize rows 1024..4095: out = sum_s Op_s / sum_s Lp_s --------------
__global__ __launch_bounds__(256) void norm_kernel(
    const float* __restrict__ Op, const float* __restrict__ Lp,
    float* __restrict__ out) {
  const int idx = blockIdx.x * 256 + threadIdx.x;  // float4 index
  const int rowg = idx >> 5, d4 = idx & 31;        // rowg 0..12287
  const int b = rowg / 3072, row = 1024 + (rowg % 3072);
  const int gr = row >> 10;  // 1..3 = chunks-1 for this row
  float ax = 0.f, ay = 0.f, az = 0.f, aw = 0.f, L = 0.f;
  for (int s = 0; s <= gr; ++s) {
    const size_t pr = (size_t)(row + slot_off(s)) * 4 + b;
    float4 o = reinterpret_cast<const float4*>(Op + pr * D_)[d4];
    ax += o.x; ay += o.y; az += o.z; aw += o.w;
    L += Lp[pr];
  }
  float4 r;
  const float inv = 1.f / L;
  r.x = ax * inv; r.y = ay * inv; r.z = az * inv; r.w = aw * inv;
  reinterpret_cast<float4*>(out + ((size_t)b * S_ + row) * D_)[d4] = r;
}

extern "C" void kernel_launch(void* const* d_in, const int* in_sizes, int n_in,
                              void* d_out, int out_size, void* d_ws, size_t ws_size,
                              hipStream_t stream) {
  const float* x = (const float*)d_in[0];
  const float* Wq = (const float*)d_in[1];
  const float* Wk = (const float*)d_in[2];
  const float* Wv = (const float*)d_in[3];
  float* out = (float*)d_out;

  char* ws = (char*)d_ws;
  unsigned short* Qb = (unsigned short*)ws;                           // 4 MB
  unsigned short* Kb = (unsigned short*)(ws + (((size_t)4) << 20));   // 4 MB
  unsigned short* VT = (unsigned short*)(ws + (((size_t)8) << 20));   // 4 MB
  unsigned short* Wt = (unsigned short*)(ws + (((size_t)12) << 20));  // 0.75 MB
  // Xb (32 MB) aliases Op (21 MB): Xb is consumed by proj BEFORE flash
  // writes Op (stream-ordered). Total workspace: ~50.5 MB.
  unsigned short* Xb = (unsigned short*)(ws + (((size_t)13) << 20));  // 32 MB
  float* Op = (float*)(ws + (((size_t)13) << 20));                    // 21 MB
  float* Lp = (float*)(ws + (((size_t)50) << 20));                    // 0.2 MB

  prep_kernel<<<8288, 256, 0, stream>>>(x, Wq, Wk, Wv, Xb, Wt);
  proj_kernel<<<768, 256, 0, stream>>>(Xb, Wt, Qb, Kb, VT);
  flash_kernel<<<640, 256, 0, stream>>>(Qb, Kb, VT, Op, Lp, out);
  norm_kernel<<<1536, 256, 0, stream>>>(Op, Lp, out);
}